// Round 1
// 588.290 us; speedup vs baseline: 1.2132x; 1.2132x over previous
//
#include <hip/hip_runtime.h>

// ---------- types / helpers ----------
typedef short bf16x8 __attribute__((ext_vector_type(8)));
typedef float f32x4 __attribute__((ext_vector_type(4)));

__device__ __forceinline__ float b2f(unsigned short u) {
  unsigned x = ((unsigned)u) << 16;
  float f;
  __builtin_memcpy(&f, &x, 4);
  return f;
}
__device__ __forceinline__ unsigned short f2b(float f) {
  unsigned x;
  __builtin_memcpy(&x, &f, 4);
  unsigned r = (x + 0x7FFFu + ((x >> 16) & 1u)) >> 16;  // RNE
  return (unsigned short)r;
}
__device__ __forceinline__ float definan(float f) {
  unsigned b;
  __builtin_memcpy(&b, &f, 4);
  if ((b & 0x7F800000u) == 0x7F800000u) return 0.f;
  return f;
}
__device__ __forceinline__ f32x4 mfma16(bf16x8 a, bf16x8 b, f32x4 c) {
  return __builtin_amdgcn_mfma_f32_16x16x32_bf16(a, b, c, 0, 0, 0);
}

#define GLL(g, l) __builtin_amdgcn_global_load_lds( \
    (const __attribute__((address_space(1))) void*)(g), \
    (__attribute__((address_space(3))) void*)(l), 16, 0, 0)

// ---------- input conversion: fp32 inputs -> bf16 arena ----------
__global__ __launch_bounds__(256)
void convert_inputs(const float* __restrict__ x, const float* __restrict__ xp,
                    const float* __restrict__ qw, const float* __restrict__ qb,
                    const float* __restrict__ pw, const float* __restrict__ pb,
                    unsigned short* __restrict__ arena) {
  long g = ((long)blockIdx.x * 256 + threadIdx.x) * 8;  // 8793*256*8 == 18008064 exactly
  const float* src;
  long off;
  if (g < 16588800L)      { src = x;  off = g; }
  else if (g < 16957440L) { src = xp; off = g - 16588800L; }
  else if (g < 17743872L) { src = qw; off = g - 16957440L; }
  else if (g < 17745408L) { src = qb; off = g - 17743872L; }
  else if (g < 18007552L) { src = pw; off = g - 17745408L; }
  else                    { src = pb; off = g - 18007552L; }
  float4 a = *(const float4*)(src + off);
  float4 b = *(const float4*)(src + off + 4);
  unsigned short o[8] = {f2b(a.x), f2b(a.y), f2b(a.z), f2b(a.w),
                         f2b(b.x), f2b(b.y), f2b(b.z), f2b(b.w)};
  uint4 pack;
  __builtin_memcpy(&pack, o, 16);
  *(uint4*)(arena + g) = pack;
}

// ---------- GEMM: C = A (MxK, row-major, bf16) * B^T (NxK, bf16) + bias ----------
__global__ __launch_bounds__(256, 2)
void gemm_bt(const unsigned short* __restrict__ A, const unsigned short* __restrict__ B,
             const unsigned short* __restrict__ bias, void* __restrict__ Co,
             int M, int K, int lda, int ldb, int ldc, int wf32) {
  __shared__ unsigned short Al[4096];
  __shared__ unsigned short Bl[4096];
  const int tid = threadIdx.x;
  const int bm = blockIdx.x, bn = blockIdx.y;
  const int lane = tid & 63;
  const int wid = tid >> 6;
  const int wm = (wid >> 1) * 64, wn = (wid & 1) * 64;
  const int mrow = lane & 15, kgrp = (lane >> 4) * 8;

  f32x4 acc[4][4] = {};

  const int c0 = tid, c1 = tid + 256;
  const int r0 = c0 >> 2, o0 = (c0 & 3) * 8;
  const int r1 = c1 >> 2, o1 = (c1 & 3) * 8;
  int am0 = bm * 128 + r0; if (am0 > M - 1) am0 = M - 1;
  int am1 = bm * 128 + r1; if (am1 > M - 1) am1 = M - 1;
  const unsigned short* ap0 = A + (size_t)am0 * lda + o0;
  const unsigned short* ap1 = A + (size_t)am1 * lda + o1;
  const unsigned short* bp0 = B + (size_t)(bn * 128 + r0) * ldb + o0;
  const unsigned short* bp1 = B + (size_t)(bn * 128 + r1) * ldb + o1;

  const int nkt = K >> 5;
  for (int kt = 0; kt < nkt; kt++) {
    GLL(ap0, &Al[c0 * 8]);
    GLL(ap1, &Al[c1 * 8]);
    GLL(bp0, &Bl[c0 * 8]);
    GLL(bp1, &Bl[c1 * 8]);
    ap0 += 32; ap1 += 32; bp0 += 32; bp1 += 32;
    __syncthreads();
    bf16x8 af[4], bfr[4];
#pragma unroll
    for (int mi = 0; mi < 4; mi++)
      af[mi] = *(const bf16x8*)&Al[(wm + mi * 16 + mrow) * 32 + kgrp];
#pragma unroll
    for (int ni = 0; ni < 4; ni++)
      bfr[ni] = *(const bf16x8*)&Bl[(wn + ni * 16 + mrow) * 32 + kgrp];
#pragma unroll
    for (int mi = 0; mi < 4; mi++)
#pragma unroll
      for (int ni = 0; ni < 4; ni++)
        acc[mi][ni] = mfma16(af[mi], bfr[ni], acc[mi][ni]);
    __syncthreads();
  }

#pragma unroll
  for (int ni = 0; ni < 4; ni++) {
    const int gcol = bn * 128 + wn + ni * 16 + mrow;
    const float bv = b2f(bias[gcol]);
#pragma unroll
    for (int mi = 0; mi < 4; mi++) {
      f32x4 v = acc[mi][ni];
#pragma unroll
      for (int r = 0; r < 4; r++) {
        int grow = bm * 128 + wm + mi * 16 + (lane >> 4) * 4 + r;
        if (grow < M) {
          float val = definan(v[r] + bv);
          if (wf32) ((float*)Co)[(size_t)grow * ldc + gcol] = val;
          else      ((unsigned short*)Co)[(size_t)grow * ldc + gcol] = f2b(val);
        }
      }
    }
  }
}

// ---------- pooled QKV: 720 tokens, only k/v, into padded (5,16,20,512) ----------
__global__ __launch_bounds__(256)
void pooled_qkv(const unsigned short* __restrict__ xp, const unsigned short* __restrict__ qw,
                const unsigned short* __restrict__ qb, unsigned short* __restrict__ kp,
                unsigned short* __restrict__ vp) {
  int gid = blockIdx.x * 256 + threadIdx.x;
  if (gid >= 720 * 1024) return;
  int n = gid & 1023, m = gid >> 10;
  int t = m / 144, rem = m - t * 144;
  int ph = rem / 12, pww = rem - ph * 12;
  const unsigned short* a = xp + (size_t)((ph * 12 + pww) * 5 + t) * 512;
  const unsigned short* b = qw + (size_t)(512 + n) * 512;
  float acc = b2f(qb[512 + n]);
#pragma unroll 4
  for (int k = 0; k < 512; k += 8) {
    uint4 av = *(const uint4*)(a + k);
    uint4 bv = *(const uint4*)(b + k);
    const unsigned short* ae = (const unsigned short*)&av;
    const unsigned short* be = (const unsigned short*)&bv;
#pragma unroll
    for (int i = 0; i < 8; i++) acc += b2f(ae[i]) * b2f(be[i]);
  }
  size_t off = ((size_t)(t * 16 + ph + 2) * 20 + (pww + 4)) * 512;
  if (n < 512) kp[off + n] = f2b(definan(acc));
  else         vp[off + n - 512] = f2b(definan(acc));
}

// ---------- fused window attention ----------
// One block per (window, q-half, head): 256 threads = 4 waves, 32 q-rows/wave.
// Pipeline per 32-key tile: issue K(t+1) via global_load_lds into double-buffered
// linear LDS (source pre-XOR-swizzled so reads are conflict-free) and V(t+1) into
// registers; compute QK/softmax/PV on tile t; barrier; swizzled V-transpose writes;
// barrier. Token offsets precomputed once into an LDS table (padded keys point at
// the guaranteed-zero head rows of kp/vp).
__global__ __launch_bounds__(256, 3)
void attn_win(const unsigned short* __restrict__ qkv, const unsigned short* __restrict__ kp,
              const unsigned short* __restrict__ vp, unsigned short* __restrict__ op) {
  const int bx = blockIdx.x, head = blockIdx.y;
  const int win = bx >> 1, qh = bx & 1;
  const int wh = win / 12, ww = win - wh * 12;
  const int tid = threadIdx.x;
  const int lane = tid & 63, wv = tid >> 6;
  const int mrow = lane & 15, kgrp = (lane >> 4) * 8;

  __shared__ unsigned short Kl[2][32 * 128];   // linear, GLL dest, chunk-XOR-swizzled
  __shared__ unsigned short VT[128 * 40];      // transposed V, key ^ (ch>>4)<<2 swizzle
  __shared__ unsigned short Plds[4 * 32 * 40]; // wave-private P staging
  __shared__ float Bias[1056];
  __shared__ int Tok[1056];                    // K element-offsets relative to qkv

  const int kpd = (int)(kp - qkv);             // pooled K region delta (elements)
  const int vpd = (int)(vp - kp);              // pooled V delta from K (elements)

  // ---- build token-offset + bias tables (once per block) ----
  for (int i = tid; i < 1056; i += 256) {
    float b = 0.f;
    int off;
    if (i < 225) {
      int t = i / 45, rem = i - t * 45;
      int ii = rem / 9, jj = rem - ii * 9;
      int g = (t * 60 + wh * 5 + ii) * 108 + ww * 9 + jj;
      off = g * 1536 + 512 + head * 128;
    } else if (i < 825) {
      int rr = i - 225;
      int t = rr / 120, v = rr - t * 120;
      int p = v / 30, q = v - p * 30;
      int ii, jj;
      if (p == 0) {
        if (q < 12) { ii = q >> 2; jj = 5 + (q & 3); }
        else { int q2 = q - 12; int d9 = q2 / 9; ii = 3 + d9; jj = q2 - d9 * 9; }
      } else if (p == 1) {
        if (q < 12) { ii = q >> 2; jj = q & 3; }
        else { int q2 = q - 12; int d9 = q2 / 9; ii = 3 + d9; jj = q2 - d9 * 9; }
      } else if (p == 2) {
        if (q < 18) { int d9 = q / 9; ii = d9; jj = q - d9 * 9; }
        else { int q2 = q - 18; ii = 2 + (q2 >> 2); jj = 5 + (q2 & 3); }
      } else {
        if (q < 18) { int d9 = q / 9; ii = d9; jj = q - d9 * 9; }
        else { int q2 = q - 18; ii = 2 + (q2 >> 2); jj = q2 & 3; }
      }
      int gh = wh * 5 + ii + ((p < 2) ? 2 : -2);
      if (gh >= 60) gh -= 60; if (gh < 0) gh += 60;
      int gw = ww * 9 + jj + (((p & 1) == 0) ? 4 : -4);
      if (gw >= 108) gw -= 108; if (gw < 0) gw += 108;
      int g = (t * 60 + gh) * 108 + gw;
      off = g * 1536 + 512 + head * 128;
    } else if (i < 1050) {
      int pidx = i - 825;
      int t = pidx / 45, rem = pidx - t * 45;
      int fi = rem / 9, fj = rem - fi * 9;
      int ph = wh + fi - 2, pw2 = ww + fj - 4;
      if (ph < 0 || ph >= 12 || pw2 < 0 || pw2 >= 12) b = -144.269504089f;  // -100*log2(e)
      off = kpd + ((t * 16 + wh + fi) * 20 + (ww + fj)) * 512 + head * 128;
    } else {
      b = -100000.f;
      off = kpd;  // kp rows < 44*512 are never written -> guaranteed zeros
    }
    Bias[i] = b;
    Tok[i] = off;
  }

  // ---- Q fragments (held in registers for whole kernel) ----
  const int qbase = qh * 128 + wv * 32;
  bf16x8 qf[2][4];
#pragma unroll
  for (int mi = 0; mi < 2; mi++) {
    int wrow = qbase + mi * 16 + mrow;
    if (wrow < 225) {
      int t = wrow / 45, rem = wrow - t * 45;
      int ii = rem / 9, jj = rem - ii * 9;
      int g = (t * 60 + wh * 5 + ii) * 108 + ww * 9 + jj;
      const unsigned short* qp = qkv + (size_t)g * 1536 + head * 128;
#pragma unroll
      for (int ks = 0; ks < 4; ks++)
        qf[mi][ks] = *(const bf16x8*)(qp + ks * 32 + kgrp);
    } else {
      bf16x8 z = {0, 0, 0, 0, 0, 0, 0, 0};
#pragma unroll
      for (int ks = 0; ks < 4; ks++) qf[mi][ks] = z;
    }
  }

  // ---- per-thread staging constants ----
  // K: 512 chunks of 16B; wave w instr i covers chunks (w*2+i)*64 + lane.
  // Dest is linear (GLL requirement); SOURCE chunk is XOR-permuted so the
  // read side's swizzled addresses see standard row-major data.
  const int ci0 = wv * 128 + lane;
  const int ci1 = ci0 + 64;
  const int kk0 = ci0 >> 4, cc0 = ((ci0 & 15) ^ (kk0 & 7)) * 8;
  const int kk1 = ci1 >> 4, cc1 = ((ci1 & 15) ^ (kk1 & 7)) * 8;
  // V: thread (srow, sch) loads 16 ch of key srow; writes transposed+swizzled.
  const int srow = tid >> 3, sch = tid & 7;
  const int kswz = srow ^ (sch << 2);

  f32x4 oacc[2][8] = {};
  f32x4 lacc[2] = {};
  bf16x8 ones;
  { short o1 = (short)0x3F80; ones = (bf16x8){o1, o1, o1, o1, o1, o1, o1, o1}; }
  const float c1 = 0.12752713f;  // log2(e)/sqrt(128)

  __syncthreads();  // Tok/Bias ready

  // ---- prologue: stage tile 0 ----
  GLL(qkv + Tok[kk0] + cc0, &Kl[0][ci0 * 8]);
  GLL(qkv + Tok[kk1] + cc1, &Kl[0][ci1 * 8]);
  uint4 vA, vB;
  {
    const unsigned short* vsrc = qkv + (size_t)Tok[srow] + 512 + sch * 16;
    vA = *(const uint4*)vsrc;
    vB = *(const uint4*)(vsrc + 8);
  }
  {
    unsigned short e[16];
    __builtin_memcpy(e, &vA, 16);
    __builtin_memcpy(e + 8, &vB, 16);
#pragma unroll
    for (int q8 = 0; q8 < 16; q8++)
      VT[(sch * 16 + q8) * 40 + kswz] = e[q8];
  }
  __syncthreads();  // barrier drains GLL (vmcnt0) + VT writes

  for (int t = 0; t < 33; t++) {
    const unsigned short* Kc = &Kl[t & 1][0];

    // ---- issue next-tile staging (hidden under this tile's compute) ----
    if (t < 32) {
      const int base = (t + 1) * 32;
      unsigned short* Kn = &Kl[(t + 1) & 1][0];
      GLL(qkv + Tok[base + kk0] + cc0, &Kn[ci0 * 8]);
      GLL(qkv + Tok[base + kk1] + cc1, &Kn[ci1 * 8]);
      int widx = base + srow;
      int vd = (widx < 825) ? 512 : vpd;
      const unsigned short* vsrc = qkv + (size_t)Tok[widx] + vd + sch * 16;
      vA = *(const uint4*)vsrc;
      vB = *(const uint4*)(vsrc + 8);
    }

    // ---- QK^T on tile t (swizzled K reads: conflict-free) ----
    f32x4 sacc[2][2] = {};
#pragma unroll
    for (int ks = 0; ks < 4; ks++) {
#pragma unroll
      for (int ni = 0; ni < 2; ni++) {
        int key = ni * 16 + mrow;
        bf16x8 kf = *(const bf16x8*)&Kc[key * 128 + ((ks * 32 + kgrp) ^ ((key & 7) << 3))];
        sacc[0][ni] = mfma16(qf[0][ks], kf, sacc[0][ni]);
        sacc[1][ni] = mfma16(qf[1][ks], kf, sacc[1][ni]);
      }
    }

    // ---- softmax numerator -> Plds (wave-private; no barrier needed) ----
    const float b0 = Bias[t * 32 + mrow];
    const float b1 = Bias[t * 32 + 16 + mrow];
#pragma unroll
    for (int mi = 0; mi < 2; mi++) {
#pragma unroll
      for (int ni = 0; ni < 2; ni++) {
        const float bb = ni ? b1 : b0;
        f32x4 s = sacc[mi][ni];
#pragma unroll
        for (int r = 0; r < 4; r++) {
          float e = definan(s[r]) * c1 + bb;
          e = fminf(e, 80.f);
          float pe = __builtin_exp2f(e);
          int prow = mi * 16 + (lane >> 4) * 4 + r;
          Plds[(wv * 32 + prow) * 40 + ni * 16 + mrow] = f2b(pe);
        }
      }
    }

    // ---- PV on tile t ----
    bf16x8 pf0 = *(const bf16x8*)&Plds[(wv * 32 + mrow) * 40 + kgrp];
    bf16x8 pf1 = *(const bf16x8*)&Plds[(wv * 32 + 16 + mrow) * 40 + kgrp];
    lacc[0] = mfma16(pf0, ones, lacc[0]);
    lacc[1] = mfma16(pf1, ones, lacc[1]);
#pragma unroll
    for (int nt = 0; nt < 8; nt++) {
      bf16x8 raw = *(const bf16x8*)&VT[(nt * 16 + mrow) * 40 + (kgrp ^ ((nt & 6) << 2))];
      bf16x8 vf = (nt & 1) ? __builtin_shufflevector(raw, raw, 4, 5, 6, 7, 0, 1, 2, 3) : raw;
      oacc[0][nt] = mfma16(pf0, vf, oacc[0][nt]);
      oacc[1][nt] = mfma16(pf1, vf, oacc[1][nt]);
    }

    __syncthreads();  // A: all waves done reading VT(t)

    if (t < 32) {
      unsigned short e[16];
      __builtin_memcpy(e, &vA, 16);
      __builtin_memcpy(e + 8, &vB, 16);
#pragma unroll
      for (int q8 = 0; q8 < 16; q8++)
        VT[(sch * 16 + q8) * 40 + kswz] = e[q8];
    }

    __syncthreads();  // B: VT(t+1) visible, K(t+1) GLL drained
  }

  // ---- epilogue ----
  const size_t obase = (size_t)win * 225;
#pragma unroll
  for (int mi = 0; mi < 2; mi++) {
    f32x4 lv = lacc[mi];
    f32x4 ri;
#pragma unroll
    for (int r = 0; r < 4; r++) ri[r] = 1.0f / fmaxf(lv[r], 1e-30f);
#pragma unroll
    for (int nt = 0; nt < 8; nt++) {
      f32x4 o = oacc[mi][nt];
#pragma unroll
      for (int r = 0; r < 4; r++) {
        int wrow = qbase + mi * 16 + (lane >> 4) * 4 + r;
        if (wrow < 225)
          op[(obase + wrow) * 512 + head * 128 + nt * 16 + mrow] = f2b(definan(o[r] * ri[r]));
      }
    }
  }
}

// ---------- launch ----------
extern "C" void kernel_launch(void* const* d_in, const int* in_sizes, int n_in,
                              void* d_out, int out_size, void* d_ws, size_t ws_size,
                              hipStream_t stream) {
  const float* x  = (const float*)d_in[0];
  const float* xp = (const float*)d_in[1];
  const float* qw = (const float*)d_in[2];
  const float* qb = (const float*)d_in[3];
  const float* pw = (const float*)d_in[4];
  const float* pb = (const float*)d_in[5];

  char* ws = (char*)d_ws;
  unsigned short* arena = (unsigned short*)ws;           // 18,008,064 el = 36,016,128 B
  unsigned short* x_b  = arena;                          // 16,588,800 el
  unsigned short* xp_b = arena + 16588800;
  unsigned short* qw_b = arena + 16957440;
  unsigned short* qb_b = arena + 17743872;
  unsigned short* pw_b = arena + 17745408;
  unsigned short* pb_b = arena + 18007552;
  unsigned short* qkv_ws = (unsigned short*)(ws + 36016128);   // 99,532,800 B
  unsigned short* kp     = (unsigned short*)(ws + 135549056);  // 1,638,400 B
  unsigned short* vp     = kp + 819200;                        // 1,638,400 B
  unsigned short* out_pre = x_b;  // overlay: x dead after gemm1

  // fp32 inputs -> bf16 arena
  convert_inputs<<<8793, 256, 0, stream>>>(x, xp, qw, qb, pw, pb, arena);

  // zero the padded pooled k/v (supplies unfold's zero padding AND the
  // guaranteed-zero rows used for padded attention keys)
  hipMemsetAsync(kp, 0, 2 * 819200 * sizeof(unsigned short), stream);

  // QKV projection for x tokens -> bf16
  dim3 g1(254, 12);
  gemm_bt<<<g1, 256, 0, stream>>>(x_b, qw_b, qb_b, qkv_ws, 32400, 512, 512, 512, 1536, 0);

  // pooled k/v
  pooled_qkv<<<2880, 256, 0, stream>>>(xp_b, qw_b, qb_b, kp, vp);

  // fused attention -> bf16 pre-projection activations
  dim3 g3(288, 4);  // (window * 2 q-halves, head)
  attn_win<<<g3, 256, 0, stream>>>(qkv_ws, kp, vp, out_pre);

  // output projection -> FLOAT32 d_out (reference output dtype)
  dim3 g4(254, 4);
  gemm_bt<<<g4, 256, 0, stream>>>(out_pre, pw_b, pb_b, d_out, 32400, 512, 512, 512, 512, 1);
}

// Round 2
// 580.649 us; speedup vs baseline: 1.2292x; 1.0132x over previous
//
#include <hip/hip_runtime.h>

// ---------- types / helpers ----------
typedef short bf16x8 __attribute__((ext_vector_type(8)));
typedef float f32x4 __attribute__((ext_vector_type(4)));

__device__ __forceinline__ float b2f(unsigned short u) {
  unsigned x = ((unsigned)u) << 16;
  float f;
  __builtin_memcpy(&f, &x, 4);
  return f;
}
__device__ __forceinline__ unsigned short f2b(float f) {
  unsigned x;
  __builtin_memcpy(&x, &f, 4);
  unsigned r = (x + 0x7FFFu + ((x >> 16) & 1u)) >> 16;  // RNE
  return (unsigned short)r;
}
__device__ __forceinline__ float definan(float f) {
  unsigned b;
  __builtin_memcpy(&b, &f, 4);
  if ((b & 0x7F800000u) == 0x7F800000u) return 0.f;
  return f;
}
__device__ __forceinline__ f32x4 mfma16(bf16x8 a, bf16x8 b, f32x4 c) {
  return __builtin_amdgcn_mfma_f32_16x16x32_bf16(a, b, c, 0, 0, 0);
}

#define GLL(g, l) __builtin_amdgcn_global_load_lds( \
    (const __attribute__((address_space(1))) void*)(g), \
    (__attribute__((address_space(3))) void*)(l), 16, 0, 0)

// ---------- input conversion: fp32 inputs -> bf16 arena ----------
__global__ __launch_bounds__(256)
void convert_inputs(const float* __restrict__ x, const float* __restrict__ xp,
                    const float* __restrict__ qw, const float* __restrict__ qb,
                    const float* __restrict__ pw, const float* __restrict__ pb,
                    unsigned short* __restrict__ arena) {
  long g = ((long)blockIdx.x * 256 + threadIdx.x) * 8;  // 8793*256*8 == 18008064 exactly
  const float* src;
  long off;
  if (g < 16588800L)      { src = x;  off = g; }
  else if (g < 16957440L) { src = xp; off = g - 16588800L; }
  else if (g < 17743872L) { src = qw; off = g - 16957440L; }
  else if (g < 17745408L) { src = qb; off = g - 17743872L; }
  else if (g < 18007552L) { src = pw; off = g - 17745408L; }
  else                    { src = pb; off = g - 18007552L; }
  float4 a = *(const float4*)(src + off);
  float4 b = *(const float4*)(src + off + 4);
  unsigned short o[8] = {f2b(a.x), f2b(a.y), f2b(a.z), f2b(a.w),
                         f2b(b.x), f2b(b.y), f2b(b.z), f2b(b.w)};
  uint4 pack;
  __builtin_memcpy(&pack, o, 16);
  *(uint4*)(arena + g) = pack;
}

// ---------- GEMM: C = A (MxK, row-major, bf16) * B^T (NxK, bf16) + bias ----------
__global__ __launch_bounds__(256, 2)
void gemm_bt(const unsigned short* __restrict__ A, const unsigned short* __restrict__ B,
             const unsigned short* __restrict__ bias, void* __restrict__ Co,
             int M, int K, int lda, int ldb, int ldc, int wf32) {
  __shared__ unsigned short Al[4096];
  __shared__ unsigned short Bl[4096];
  const int tid = threadIdx.x;
  const int bm = blockIdx.x, bn = blockIdx.y;
  const int lane = tid & 63;
  const int wid = tid >> 6;
  const int wm = (wid >> 1) * 64, wn = (wid & 1) * 64;
  const int mrow = lane & 15, kgrp = (lane >> 4) * 8;

  f32x4 acc[4][4] = {};

  const int c0 = tid, c1 = tid + 256;
  const int r0 = c0 >> 2, o0 = (c0 & 3) * 8;
  const int r1 = c1 >> 2, o1 = (c1 & 3) * 8;
  int am0 = bm * 128 + r0; if (am0 > M - 1) am0 = M - 1;
  int am1 = bm * 128 + r1; if (am1 > M - 1) am1 = M - 1;
  const unsigned short* ap0 = A + (size_t)am0 * lda + o0;
  const unsigned short* ap1 = A + (size_t)am1 * lda + o1;
  const unsigned short* bp0 = B + (size_t)(bn * 128 + r0) * ldb + o0;
  const unsigned short* bp1 = B + (size_t)(bn * 128 + r1) * ldb + o1;

  const int nkt = K >> 5;
  for (int kt = 0; kt < nkt; kt++) {
    GLL(ap0, &Al[c0 * 8]);
    GLL(ap1, &Al[c1 * 8]);
    GLL(bp0, &Bl[c0 * 8]);
    GLL(bp1, &Bl[c1 * 8]);
    ap0 += 32; ap1 += 32; bp0 += 32; bp1 += 32;
    __syncthreads();
    bf16x8 af[4], bfr[4];
#pragma unroll
    for (int mi = 0; mi < 4; mi++)
      af[mi] = *(const bf16x8*)&Al[(wm + mi * 16 + mrow) * 32 + kgrp];
#pragma unroll
    for (int ni = 0; ni < 4; ni++)
      bfr[ni] = *(const bf16x8*)&Bl[(wn + ni * 16 + mrow) * 32 + kgrp];
#pragma unroll
    for (int mi = 0; mi < 4; mi++)
#pragma unroll
      for (int ni = 0; ni < 4; ni++)
        acc[mi][ni] = mfma16(af[mi], bfr[ni], acc[mi][ni]);
    __syncthreads();
  }

#pragma unroll
  for (int ni = 0; ni < 4; ni++) {
    const int gcol = bn * 128 + wn + ni * 16 + mrow;
    const float bv = b2f(bias[gcol]);
#pragma unroll
    for (int mi = 0; mi < 4; mi++) {
      f32x4 v = acc[mi][ni];
#pragma unroll
      for (int r = 0; r < 4; r++) {
        int grow = bm * 128 + wm + mi * 16 + (lane >> 4) * 4 + r;
        if (grow < M) {
          float val = definan(v[r] + bv);
          if (wf32) ((float*)Co)[(size_t)grow * ldc + gcol] = val;
          else      ((unsigned short*)Co)[(size_t)grow * ldc + gcol] = f2b(val);
        }
      }
    }
  }
}

// ---------- pooled QKV: 720 tokens, only k/v, into padded (5,16,20,512) ----------
__global__ __launch_bounds__(256)
void pooled_qkv(const unsigned short* __restrict__ xp, const unsigned short* __restrict__ qw,
                const unsigned short* __restrict__ qb, unsigned short* __restrict__ kp,
                unsigned short* __restrict__ vp) {
  int gid = blockIdx.x * 256 + threadIdx.x;
  if (gid >= 720 * 1024) return;
  int n = gid & 1023, m = gid >> 10;
  int t = m / 144, rem = m - t * 144;
  int ph = rem / 12, pww = rem - ph * 12;
  const unsigned short* a = xp + (size_t)((ph * 12 + pww) * 5 + t) * 512;
  const unsigned short* b = qw + (size_t)(512 + n) * 512;
  float acc = b2f(qb[512 + n]);
#pragma unroll 4
  for (int k = 0; k < 512; k += 8) {
    uint4 av = *(const uint4*)(a + k);
    uint4 bv = *(const uint4*)(b + k);
    const unsigned short* ae = (const unsigned short*)&av;
    const unsigned short* be = (const unsigned short*)&bv;
#pragma unroll
    for (int i = 0; i < 8; i++) acc += b2f(ae[i]) * b2f(be[i]);
  }
  size_t off = ((size_t)(t * 16 + ph + 2) * 20 + (pww + 4)) * 512;
  if (n < 512) kp[off + n] = f2b(definan(acc));
  else         vp[off + n - 512] = f2b(definan(acc));
}

// ---------- fused window attention ----------
// One block per (window, q-half, head): 256 threads = 4 waves, 32 q-rows/wave.
// XCD-swizzled 1-D grid: all 8 blocks of a window (2 qh x 4 heads) plus 18
// neighbor windows share one XCD's L2.
// Per 32-key tile, ONE barrier: K double-buffered via global_load_lds
// (pre-swizzled source), V double-buffered transposed in LDS; P kept fully
// in registers via swapped QK^T (mfma(K,Q)) + v_cvt_pk_bf16_f32 +
// v_permlane32_swap_b32 fragment assembly. A static key permutation (blocks
// 1<->2 of each 16, applied at V staging) makes the permlane exchange yield
// exactly the PV A-fragment order.
__global__ __launch_bounds__(256, 3)
void attn_win(const unsigned short* __restrict__ qkv, const unsigned short* __restrict__ kp,
              const unsigned short* __restrict__ vp, unsigned short* __restrict__ op) {
  const int bi = blockIdx.x;
  const int win = (bi & 7) * 18 + (bi >> 6);       // i>>3 in 0..143, /8 -> 0..17
  const int sub = (bi >> 3) & 7;
  const int qh = sub & 1, head = sub >> 1;
  const int wh = win / 12, ww = win - wh * 12;
  const int tid = threadIdx.x;
  const int lane = tid & 63, wv = tid >> 6;
  const int mrow = lane & 15, kgrp = (lane >> 4) * 8;
  const int lg = lane >> 4;

  __shared__ unsigned short Kl[2][32 * 128];   // linear GLL dest, chunk-XOR-swizzled
  __shared__ unsigned short VT[2][128 * 40];   // transposed V, col ^ (sch<<2) swizzle
  __shared__ float Bias[1056];
  __shared__ int Tok[1056];                    // K element-offsets relative to qkv

  const int kpd = (int)(kp - qkv);             // pooled K region delta (elements)
  const int vpd = (int)(vp - kp);              // pooled V delta from K (elements)

  // ---- build token-offset + bias tables (once per block) ----
  for (int i = tid; i < 1056; i += 256) {
    float b = 0.f;
    int off;
    if (i < 225) {
      int t = i / 45, rem = i - t * 45;
      int ii = rem / 9, jj = rem - ii * 9;
      int g = (t * 60 + wh * 5 + ii) * 108 + ww * 9 + jj;
      off = g * 1536 + 512 + head * 128;
    } else if (i < 825) {
      int rr = i - 225;
      int t = rr / 120, v = rr - t * 120;
      int p = v / 30, q = v - p * 30;
      int ii, jj;
      if (p == 0) {
        if (q < 12) { ii = q >> 2; jj = 5 + (q & 3); }
        else { int q2 = q - 12; int d9 = q2 / 9; ii = 3 + d9; jj = q2 - d9 * 9; }
      } else if (p == 1) {
        if (q < 12) { ii = q >> 2; jj = q & 3; }
        else { int q2 = q - 12; int d9 = q2 / 9; ii = 3 + d9; jj = q2 - d9 * 9; }
      } else if (p == 2) {
        if (q < 18) { int d9 = q / 9; ii = d9; jj = q - d9 * 9; }
        else { int q2 = q - 18; ii = 2 + (q2 >> 2); jj = 5 + (q2 & 3); }
      } else {
        if (q < 18) { int d9 = q / 9; ii = d9; jj = q - d9 * 9; }
        else { int q2 = q - 18; ii = 2 + (q2 >> 2); jj = q2 & 3; }
      }
      int gh = wh * 5 + ii + ((p < 2) ? 2 : -2);
      if (gh >= 60) gh -= 60; if (gh < 0) gh += 60;
      int gw = ww * 9 + jj + (((p & 1) == 0) ? 4 : -4);
      if (gw >= 108) gw -= 108; if (gw < 0) gw += 108;
      int g = (t * 60 + gh) * 108 + gw;
      off = g * 1536 + 512 + head * 128;
    } else if (i < 1050) {
      int pidx = i - 825;
      int t = pidx / 45, rem = pidx - t * 45;
      int fi = rem / 9, fj = rem - fi * 9;
      int ph = wh + fi - 2, pw2 = ww + fj - 4;
      if (ph < 0 || ph >= 12 || pw2 < 0 || pw2 >= 12) b = -144.269504089f;  // -100*log2(e)
      off = kpd + ((t * 16 + wh + fi) * 20 + (ww + fj)) * 512 + head * 128;
    } else {
      b = -100000.f;
      off = kpd;  // kp/vp rows < 44*512 are never written -> guaranteed zeros
    }
    Bias[i] = b;
    Tok[i] = off;
  }

  // ---- Q fragments (held in registers for whole kernel) ----
  const int qbase = qh * 128 + wv * 32;
  bf16x8 qf[2][4];
#pragma unroll
  for (int mi = 0; mi < 2; mi++) {
    int wrow = qbase + mi * 16 + mrow;
    if (wrow < 225) {
      int t = wrow / 45, rem = wrow - t * 45;
      int ii = rem / 9, jj = rem - ii * 9;
      int g = (t * 60 + wh * 5 + ii) * 108 + ww * 9 + jj;
      const unsigned short* qp = qkv + (size_t)g * 1536 + head * 128;
#pragma unroll
      for (int ks = 0; ks < 4; ks++)
        qf[mi][ks] = *(const bf16x8*)(qp + ks * 32 + kgrp);
    } else {
      bf16x8 z = {0, 0, 0, 0, 0, 0, 0, 0};
#pragma unroll
      for (int ks = 0; ks < 4; ks++) qf[mi][ks] = z;
    }
  }

  // ---- per-thread staging constants ----
  // K: 512 chunks of 16B; dest linear (GLL), SOURCE chunk XOR-permuted so the
  // swizzled read addresses see row-major data.
  const int ci0 = wv * 128 + lane;
  const int ci1 = ci0 + 64;
  const int kk0 = ci0 >> 4, cc0 = ((ci0 & 15) ^ (kk0 & 7)) * 8;
  const int kk1 = ci1 >> 4, cc1 = ((ci1 & 15) ^ (kk1 & 7)) * 8;
  // V: thread (srow, sch) loads 16 ch of VT-column srow; the PHYSICAL key for
  // fragment position p swaps blocks 1<->2 within each 16 (permlane layout).
  const int srow = tid >> 3, sch = tid & 7;
  const int kswz = srow ^ (sch << 2);
  const int sb = (srow >> 2) & 3;
  const int dsrow = srow + (sb == 1 ? 4 : (sb == 2 ? -4 : 0));

  f32x4 oacc[2][8] = {};
  f32x4 lacc[2] = {};
  bf16x8 ones;
  { short o1 = (short)0x3F80; ones = (bf16x8){o1, o1, o1, o1, o1, o1, o1, o1}; }
  const float c1 = 0.12752713f;  // log2(e)/sqrt(128)

  __syncthreads();  // Tok/Bias ready

  // ---- prologue: stage tile 0 ----
  GLL(qkv + Tok[kk0] + cc0, &Kl[0][ci0 * 8]);
  GLL(qkv + Tok[kk1] + cc1, &Kl[0][ci1 * 8]);
  {
    const unsigned short* vsrc = qkv + (size_t)Tok[dsrow] + 512 + sch * 16;
    uint4 vA = *(const uint4*)vsrc;
    uint4 vB = *(const uint4*)(vsrc + 8);
    unsigned short e[16];
    __builtin_memcpy(e, &vA, 16);
    __builtin_memcpy(e + 8, &vB, 16);
#pragma unroll
    for (int q8 = 0; q8 < 16; q8++)
      VT[0][(sch * 16 + q8) * 40 + kswz] = e[q8];
  }
  __syncthreads();  // drains GLL + VT writes

  for (int t = 0; t < 33; t++) {
    const int cur = t & 1, nxt = cur ^ 1;
    const unsigned short* Kc = &Kl[cur][0];

    // ---- issue next-tile staging (hidden under this tile's compute) ----
    uint4 vA, vB;
    if (t < 32) {
      const int base = (t + 1) * 32;
      GLL(qkv + Tok[base + kk0] + cc0, &Kl[nxt][ci0 * 8]);
      GLL(qkv + Tok[base + kk1] + cc1, &Kl[nxt][ci1 * 8]);
      int widx = base + dsrow;
      int vd = (widx < 825) ? 512 : vpd;
      const unsigned short* vsrc = qkv + (size_t)Tok[widx] + vd + sch * 16;
      vA = *(const uint4*)vsrc;
      vB = *(const uint4*)(vsrc + 8);
    }

    // ---- S^T = K·Q^T on tile t (swapped operands; swizzled K reads) ----
    f32x4 sacc[2][2] = {};
    __builtin_amdgcn_s_setprio(1);
#pragma unroll
    for (int ks = 0; ks < 4; ks++) {
#pragma unroll
      for (int ni = 0; ni < 2; ni++) {
        int key = ni * 16 + mrow;
        bf16x8 kf = *(const bf16x8*)&Kc[key * 128 + ((ks * 32 + kgrp) ^ ((key & 7) << 3))];
        sacc[0][ni] = mfma16(kf, qf[0][ks], sacc[0][ni]);
        sacc[1][ni] = mfma16(kf, qf[1][ks], sacc[1][ni]);
      }
    }
    __builtin_amdgcn_s_setprio(0);

    // ---- softmax numerator fully in registers -> PV A-fragments ----
    // lane (g,mrow): sacc[mi][ni][r] = S[key = t*32+ni*16+4g+r][q = mi-tile mrow]
    bf16x8 pf[2];
#pragma unroll
    for (int mi = 0; mi < 2; mi++) {
      unsigned u[4];
#pragma unroll
      for (int ni = 0; ni < 2; ni++) {
        const float4 bb = *(const float4*)&Bias[t * 32 + ni * 16 + lg * 4];
        f32x4 s = sacc[mi][ni];
        float p0 = __builtin_exp2f(fminf(definan(s[0]) * c1 + bb.x, 80.f));
        float p1 = __builtin_exp2f(fminf(definan(s[1]) * c1 + bb.y, 80.f));
        float p2 = __builtin_exp2f(fminf(definan(s[2]) * c1 + bb.z, 80.f));
        float p3 = __builtin_exp2f(fminf(definan(s[3]) * c1 + bb.w, 80.f));
        unsigned ua, ub;
        asm("v_cvt_pk_bf16_f32 %0, %1, %2" : "=v"(ua) : "v"(p0), "v"(p1));
        asm("v_cvt_pk_bf16_f32 %0, %1, %2" : "=v"(ub) : "v"(p2), "v"(p3));
        u[ni * 2 + 0] = ua;
        u[ni * 2 + 1] = ub;
      }
      // exchange groups 0<->2, 1<->3; with the dsrow key-perm this yields
      // fragment words (j01,j23,j45,j67) = (u0,u1,u2,u3) for ALL lanes.
      asm("v_permlane32_swap_b32 %0, %1" : "+v"(u[0]), "+v"(u[2]));
      asm("v_permlane32_swap_b32 %0, %1" : "+v"(u[1]), "+v"(u[3]));
      __builtin_memcpy(&pf[mi], u, 16);
    }

    // ---- PV on tile t ----
    __builtin_amdgcn_s_setprio(1);
    lacc[0] = mfma16(pf[0], ones, lacc[0]);
    lacc[1] = mfma16(pf[1], ones, lacc[1]);
#pragma unroll
    for (int nt = 0; nt < 8; nt++) {
      bf16x8 raw = *(const bf16x8*)&VT[cur][(nt * 16 + mrow) * 40 + (kgrp ^ ((nt & 6) << 2))];
      bf16x8 vf = (nt & 1) ? __builtin_shufflevector(raw, raw, 4, 5, 6, 7, 0, 1, 2, 3) : raw;
      oacc[0][nt] = mfma16(pf[0], vf, oacc[0][nt]);
      oacc[1][nt] = mfma16(pf[1], vf, oacc[1][nt]);
    }
    __builtin_amdgcn_s_setprio(0);

    // ---- V(t+1) transpose into the other buffer ----
    if (t < 32) {
      unsigned short e[16];
      __builtin_memcpy(e, &vA, 16);
      __builtin_memcpy(e + 8, &vB, 16);
#pragma unroll
      for (int q8 = 0; q8 < 16; q8++)
        VT[nxt][(sch * 16 + q8) * 40 + kswz] = e[q8];
    }

    __syncthreads();  // single barrier: drains K-GLL(t+1) + VT(t+1) writes
  }

  // ---- epilogue ----
  const size_t obase = (size_t)win * 225;
#pragma unroll
  for (int mi = 0; mi < 2; mi++) {
    f32x4 lv = lacc[mi];
    f32x4 ri;
#pragma unroll
    for (int r = 0; r < 4; r++) ri[r] = 1.0f / fmaxf(lv[r], 1e-30f);
#pragma unroll
    for (int nt = 0; nt < 8; nt++) {
      f32x4 o = oacc[mi][nt];
#pragma unroll
      for (int r = 0; r < 4; r++) {
        int wrow = qbase + mi * 16 + (lane >> 4) * 4 + r;
        if (wrow < 225)
          op[(obase + wrow) * 512 + head * 128 + nt * 16 + mrow] = f2b(definan(o[r] * ri[r]));
      }
    }
  }
}

// ---------- launch ----------
extern "C" void kernel_launch(void* const* d_in, const int* in_sizes, int n_in,
                              void* d_out, int out_size, void* d_ws, size_t ws_size,
                              hipStream_t stream) {
  const float* x  = (const float*)d_in[0];
  const float* xp = (const float*)d_in[1];
  const float* qw = (const float*)d_in[2];
  const float* qb = (const float*)d_in[3];
  const float* pw = (const float*)d_in[4];
  const float* pb = (const float*)d_in[5];

  char* ws = (char*)d_ws;
  unsigned short* arena = (unsigned short*)ws;           // 18,008,064 el = 36,016,128 B
  unsigned short* x_b  = arena;                          // 16,588,800 el
  unsigned short* xp_b = arena + 16588800;
  unsigned short* qw_b = arena + 16957440;
  unsigned short* qb_b = arena + 17743872;
  unsigned short* pw_b = arena + 17745408;
  unsigned short* pb_b = arena + 18007552;
  unsigned short* qkv_ws = (unsigned short*)(ws + 36016128);   // 99,532,800 B
  unsigned short* kp     = (unsigned short*)(ws + 135549056);  // 1,638,400 B
  unsigned short* vp     = kp + 819200;                        // 1,638,400 B
  unsigned short* out_pre = x_b;  // overlay: x dead after gemm1

  // fp32 inputs -> bf16 arena
  convert_inputs<<<8793, 256, 0, stream>>>(x, xp, qw, qb, pw, pb, arena);

  // zero the padded pooled k/v (supplies unfold's zero padding AND the
  // guaranteed-zero rows used for padded attention keys)
  hipMemsetAsync(kp, 0, 2 * 819200 * sizeof(unsigned short), stream);

  // QKV projection for x tokens -> bf16
  dim3 g1(254, 12);
  gemm_bt<<<g1, 256, 0, stream>>>(x_b, qw_b, qb_b, qkv_ws, 32400, 512, 512, 512, 1536, 0);

  // pooled k/v
  pooled_qkv<<<2880, 256, 0, stream>>>(xp_b, qw_b, qb_b, kp, vp);

  // fused attention -> bf16 pre-projection activations (XCD-swizzled 1-D grid)
  attn_win<<<1152, 256, 0, stream>>>(qkv_ws, kp, vp, out_pre);

  // output projection -> FLOAT32 d_out (reference output dtype)
  dim3 g4(254, 4);
  gemm_bt<<<g4, 256, 0, stream>>>(out_pre, pw_b, pb_b, d_out, 32400, 512, 512, 512, 512, 1);
}

// Round 3
// 531.194 us; speedup vs baseline: 1.3436x; 1.0931x over previous
//
#include <hip/hip_runtime.h>

// ---------- types / helpers ----------
typedef short bf16x8 __attribute__((ext_vector_type(8)));
typedef float f32x4 __attribute__((ext_vector_type(4)));

__device__ __forceinline__ float b2f(unsigned short u) {
  unsigned x = ((unsigned)u) << 16;
  float f;
  __builtin_memcpy(&f, &x, 4);
  return f;
}
__device__ __forceinline__ unsigned short f2b(float f) {
  unsigned x;
  __builtin_memcpy(&x, &f, 4);
  unsigned r = (x + 0x7FFFu + ((x >> 16) & 1u)) >> 16;  // RNE
  return (unsigned short)r;
}
__device__ __forceinline__ float definan(float f) {
  unsigned b;
  __builtin_memcpy(&b, &f, 4);
  if ((b & 0x7F800000u) == 0x7F800000u) return 0.f;
  return f;
}
__device__ __forceinline__ f32x4 mfma16(bf16x8 a, bf16x8 b, f32x4 c) {
  return __builtin_amdgcn_mfma_f32_16x16x32_bf16(a, b, c, 0, 0, 0);
}

#define GLL(g, l) __builtin_amdgcn_global_load_lds( \
    (const __attribute__((address_space(1))) void*)(g), \
    (__attribute__((address_space(3))) void*)(l), 16, 0, 0)

// ---------- input conversion: fp32 inputs -> bf16 arena ----------
__global__ __launch_bounds__(256)
void convert_inputs(const float* __restrict__ x, const float* __restrict__ xp,
                    const float* __restrict__ qw, const float* __restrict__ qb,
                    const float* __restrict__ pw, const float* __restrict__ pb,
                    unsigned short* __restrict__ arena) {
  long g = ((long)blockIdx.x * 256 + threadIdx.x) * 8;  // 8793*256*8 == 18008064 exactly
  const float* src;
  long off;
  if (g < 16588800L)      { src = x;  off = g; }
  else if (g < 16957440L) { src = xp; off = g - 16588800L; }
  else if (g < 17743872L) { src = qw; off = g - 16957440L; }
  else if (g < 17745408L) { src = qb; off = g - 17743872L; }
  else if (g < 18007552L) { src = pw; off = g - 17745408L; }
  else                    { src = pb; off = g - 18007552L; }
  float4 a = *(const float4*)(src + off);
  float4 b = *(const float4*)(src + off + 4);
  unsigned short o[8] = {f2b(a.x), f2b(a.y), f2b(a.z), f2b(a.w),
                         f2b(b.x), f2b(b.y), f2b(b.z), f2b(b.w)};
  uint4 pack;
  __builtin_memcpy(&pack, o, 16);
  *(uint4*)(arena + g) = pack;
}

// ---------- GEMM: C = A (MxK, row-major, bf16) * B^T (NxK, bf16) + bias ----------
// 1-D grid, XCD-chunked: each XCD gets a contiguous (bm-major, bn-fast) range so
// the A-tile is L2-resident across its bn-blocks. gridDim.x must be %8 == 0.
__global__ __launch_bounds__(256, 2)
void gemm_bt(const unsigned short* __restrict__ A, const unsigned short* __restrict__ B,
             const unsigned short* __restrict__ bias, void* __restrict__ Co,
             int M, int K, int lda, int ldb, int ldc, int wf32, int nbn) {
  __shared__ unsigned short Al[4096];
  __shared__ unsigned short Bl[4096];
  const int tid = threadIdx.x;
  const int i = blockIdx.x;
  const int g = (i & 7) * ((int)gridDim.x >> 3) + (i >> 3);
  const int bm = g / nbn, bn = g - bm * nbn;
  const int lane = tid & 63;
  const int wid = tid >> 6;
  const int wm = (wid >> 1) * 64, wn = (wid & 1) * 64;
  const int mrow = lane & 15, kgrp = (lane >> 4) * 8;

  f32x4 acc[4][4] = {};

  const int c0 = tid, c1 = tid + 256;
  const int r0 = c0 >> 2, o0 = (c0 & 3) * 8;
  const int r1 = c1 >> 2, o1 = (c1 & 3) * 8;
  int am0 = bm * 128 + r0; if (am0 > M - 1) am0 = M - 1;
  int am1 = bm * 128 + r1; if (am1 > M - 1) am1 = M - 1;
  const unsigned short* ap0 = A + (size_t)am0 * lda + o0;
  const unsigned short* ap1 = A + (size_t)am1 * lda + o1;
  const unsigned short* bp0 = B + (size_t)(bn * 128 + r0) * ldb + o0;
  const unsigned short* bp1 = B + (size_t)(bn * 128 + r1) * ldb + o1;

  const int nkt = K >> 5;
  for (int kt = 0; kt < nkt; kt++) {
    GLL(ap0, &Al[c0 * 8]);
    GLL(ap1, &Al[c1 * 8]);
    GLL(bp0, &Bl[c0 * 8]);
    GLL(bp1, &Bl[c1 * 8]);
    ap0 += 32; ap1 += 32; bp0 += 32; bp1 += 32;
    __syncthreads();
    bf16x8 af[4], bfr[4];
#pragma unroll
    for (int mi = 0; mi < 4; mi++)
      af[mi] = *(const bf16x8*)&Al[(wm + mi * 16 + mrow) * 32 + kgrp];
#pragma unroll
    for (int ni = 0; ni < 4; ni++)
      bfr[ni] = *(const bf16x8*)&Bl[(wn + ni * 16 + mrow) * 32 + kgrp];
#pragma unroll
    for (int mi = 0; mi < 4; mi++)
#pragma unroll
      for (int ni = 0; ni < 4; ni++)
        acc[mi][ni] = mfma16(af[mi], bfr[ni], acc[mi][ni]);
    __syncthreads();
  }

#pragma unroll
  for (int ni = 0; ni < 4; ni++) {
    const int gcol = bn * 128 + wn + ni * 16 + mrow;
    const float bv = b2f(bias[gcol]);
#pragma unroll
    for (int mi = 0; mi < 4; mi++) {
      f32x4 v = acc[mi][ni];
#pragma unroll
      for (int r = 0; r < 4; r++) {
        int grow = bm * 128 + wm + mi * 16 + (lane >> 4) * 4 + r;
        if (grow < M) {
          float val = definan(v[r] + bv);
          if (wf32) ((float*)Co)[(size_t)grow * ldc + gcol] = val;
          else      ((unsigned short*)Co)[(size_t)grow * ldc + gcol] = f2b(val);
        }
      }
    }
  }
}

// ---------- pooled QKV: 720 tokens, only k/v, into padded (5,16,20,512) ----------
__global__ __launch_bounds__(256)
void pooled_qkv(const unsigned short* __restrict__ xp, const unsigned short* __restrict__ qw,
                const unsigned short* __restrict__ qb, unsigned short* __restrict__ kp,
                unsigned short* __restrict__ vp) {
  int gid = blockIdx.x * 256 + threadIdx.x;
  if (gid >= 720 * 1024) return;
  int n = gid & 1023, m = gid >> 10;
  int t = m / 144, rem = m - t * 144;
  int ph = rem / 12, pww = rem - ph * 12;
  const unsigned short* a = xp + (size_t)((ph * 12 + pww) * 5 + t) * 512;
  const unsigned short* b = qw + (size_t)(512 + n) * 512;
  float acc = b2f(qb[512 + n]);
#pragma unroll 4
  for (int k = 0; k < 512; k += 8) {
    uint4 av = *(const uint4*)(a + k);
    uint4 bv = *(const uint4*)(b + k);
    const unsigned short* ae = (const unsigned short*)&av;
    const unsigned short* be = (const unsigned short*)&bv;
#pragma unroll
    for (int i = 0; i < 8; i++) acc += b2f(ae[i]) * b2f(be[i]);
  }
  size_t off = ((size_t)(t * 16 + ph + 2) * 20 + (pww + 4)) * 512;
  if (n < 512) kp[off + n] = f2b(definan(acc));
  else         vp[off + n - 512] = f2b(definan(acc));
}

// ---------- fused window attention ----------
// One block per (window, q-half, head): 256 threads = 4 waves, 32 q-rows/wave.
// XCD-swizzled 1-D grid; single barrier per 32-key tile; K via double-buffered
// global_load_lds (pre-swizzled source); V double-buffered transposed in LDS;
// P fully in registers via swapped QK^T + cvt_pk + permlane32_swap.
// Softmax denominator via VALU cross-lane reduce (no mfma-with-ones, no lacc):
// keeps total unified VGPR+AGPR <= 170 -> 3 waves/SIMD.
__global__ __launch_bounds__(256, 3)
void attn_win(const unsigned short* __restrict__ qkv, const unsigned short* __restrict__ kp,
              const unsigned short* __restrict__ vp, unsigned short* __restrict__ op) {
  const int bi = blockIdx.x;
  const int win = (bi & 7) * 18 + (bi >> 6);
  const int sub = (bi >> 3) & 7;
  const int qh = sub & 1, head = sub >> 1;
  const int wh = win / 12, ww = win - wh * 12;
  const int tid = threadIdx.x;
  const int lane = tid & 63, wv = tid >> 6;
  const int mrow = lane & 15, kgrp = (lane >> 4) * 8;
  const int lg = lane >> 4;

  __shared__ unsigned short Kl[2][32 * 128];   // linear GLL dest, chunk-XOR-swizzled
  __shared__ unsigned short VT[2][128 * 40];   // transposed V, col ^ (sch<<2) swizzle
  __shared__ float Bias[1056];
  __shared__ int Tok[1056];                    // K element-offsets relative to qkv

  const int kpd = (int)(kp - qkv);             // pooled K region delta (elements)
  const int vpd = (int)(vp - kp);              // pooled V delta from K (elements)

  // ---- build token-offset + bias tables (once per block) ----
  for (int i = tid; i < 1056; i += 256) {
    float b = 0.f;
    int off;
    if (i < 225) {
      int t = i / 45, rem = i - t * 45;
      int ii = rem / 9, jj = rem - ii * 9;
      int g = (t * 60 + wh * 5 + ii) * 108 + ww * 9 + jj;
      off = g * 1536 + 512 + head * 128;
    } else if (i < 825) {
      int rr = i - 225;
      int t = rr / 120, v = rr - t * 120;
      int p = v / 30, q = v - p * 30;
      int ii, jj;
      if (p == 0) {
        if (q < 12) { ii = q >> 2; jj = 5 + (q & 3); }
        else { int q2 = q - 12; int d9 = q2 / 9; ii = 3 + d9; jj = q2 - d9 * 9; }
      } else if (p == 1) {
        if (q < 12) { ii = q >> 2; jj = q & 3; }
        else { int q2 = q - 12; int d9 = q2 / 9; ii = 3 + d9; jj = q2 - d9 * 9; }
      } else if (p == 2) {
        if (q < 18) { int d9 = q / 9; ii = d9; jj = q - d9 * 9; }
        else { int q2 = q - 18; ii = 2 + (q2 >> 2); jj = 5 + (q2 & 3); }
      } else {
        if (q < 18) { int d9 = q / 9; ii = d9; jj = q - d9 * 9; }
        else { int q2 = q - 18; ii = 2 + (q2 >> 2); jj = q2 & 3; }
      }
      int gh = wh * 5 + ii + ((p < 2) ? 2 : -2);
      if (gh >= 60) gh -= 60; if (gh < 0) gh += 60;
      int gw = ww * 9 + jj + (((p & 1) == 0) ? 4 : -4);
      if (gw >= 108) gw -= 108; if (gw < 0) gw += 108;
      int g = (t * 60 + gh) * 108 + gw;
      off = g * 1536 + 512 + head * 128;
    } else if (i < 1050) {
      int pidx = i - 825;
      int t = pidx / 45, rem = pidx - t * 45;
      int fi = rem / 9, fj = rem - fi * 9;
      int ph = wh + fi - 2, pw2 = ww + fj - 4;
      if (ph < 0 || ph >= 12 || pw2 < 0 || pw2 >= 12) b = -144.269504089f;  // -100*log2(e)
      off = kpd + ((t * 16 + wh + fi) * 20 + (ww + fj)) * 512 + head * 128;
    } else {
      b = -100000.f;
      off = kpd;  // kp/vp rows < 44*512 are never written -> guaranteed zeros
    }
    Bias[i] = b;
    Tok[i] = off;
  }

  // ---- Q fragments (held in registers for whole kernel) ----
  const int qbase = qh * 128 + wv * 32;
  bf16x8 qf[2][4];
#pragma unroll
  for (int mi = 0; mi < 2; mi++) {
    int wrow = qbase + mi * 16 + mrow;
    if (wrow < 225) {
      int t = wrow / 45, rem = wrow - t * 45;
      int ii = rem / 9, jj = rem - ii * 9;
      int g = (t * 60 + wh * 5 + ii) * 108 + ww * 9 + jj;
      const unsigned short* qp = qkv + (size_t)g * 1536 + head * 128;
#pragma unroll
      for (int ks = 0; ks < 4; ks++)
        qf[mi][ks] = *(const bf16x8*)(qp + ks * 32 + kgrp);
    } else {
      bf16x8 z = {0, 0, 0, 0, 0, 0, 0, 0};
#pragma unroll
      for (int ks = 0; ks < 4; ks++) qf[mi][ks] = z;
    }
  }

  // ---- per-thread staging constants ----
  const int ci0 = wv * 128 + lane;
  const int ci1 = ci0 + 64;
  const int kk0 = ci0 >> 4, cc0 = ((ci0 & 15) ^ (kk0 & 7)) * 8;
  const int kk1 = ci1 >> 4, cc1 = ((ci1 & 15) ^ (kk1 & 7)) * 8;
  const int srow = tid >> 3, sch = tid & 7;
  const int kswz = srow ^ (sch << 2);
  const int sb = (srow >> 2) & 3;
  const int dsrow = srow + (sb == 1 ? 4 : (sb == 2 ? -4 : 0));

  f32x4 oacc[2][8] = {};
  float lsum[2] = {0.f, 0.f};  // softmax denom per q-row (lane-indexed by mrow)
  const float c1 = 0.12752713f;  // log2(e)/sqrt(128)

  __syncthreads();  // Tok/Bias ready

  // ---- prologue: stage tile 0 ----
  GLL(qkv + Tok[kk0] + cc0, &Kl[0][ci0 * 8]);
  GLL(qkv + Tok[kk1] + cc1, &Kl[0][ci1 * 8]);
  {
    const unsigned short* vsrc = qkv + (size_t)Tok[dsrow] + 512 + sch * 16;
    uint4 vA = *(const uint4*)vsrc;
    uint4 vB = *(const uint4*)(vsrc + 8);
    unsigned short e[16];
    __builtin_memcpy(e, &vA, 16);
    __builtin_memcpy(e + 8, &vB, 16);
#pragma unroll
    for (int q8 = 0; q8 < 16; q8++)
      VT[0][(sch * 16 + q8) * 40 + kswz] = e[q8];
  }
  __syncthreads();  // drains GLL + VT writes

  for (int t = 0; t < 33; t++) {
    const int cur = t & 1, nxt = cur ^ 1;
    const unsigned short* Kc = &Kl[cur][0];

    // ---- issue next-tile staging (hidden under this tile's compute) ----
    uint4 vA, vB;
    if (t < 32) {
      const int base = (t + 1) * 32;
      GLL(qkv + Tok[base + kk0] + cc0, &Kl[nxt][ci0 * 8]);
      GLL(qkv + Tok[base + kk1] + cc1, &Kl[nxt][ci1 * 8]);
      int widx = base + dsrow;
      int vd = (widx < 825) ? 512 : vpd;
      const unsigned short* vsrc = qkv + (size_t)Tok[widx] + vd + sch * 16;
      vA = *(const uint4*)vsrc;
      vB = *(const uint4*)(vsrc + 8);
    }

    // ---- S^T = K·Q^T on tile t (swapped operands; swizzled K reads) ----
    f32x4 sacc[2][2] = {};
    __builtin_amdgcn_s_setprio(1);
#pragma unroll
    for (int ks = 0; ks < 4; ks++) {
#pragma unroll
      for (int ni = 0; ni < 2; ni++) {
        int key = ni * 16 + mrow;
        bf16x8 kf = *(const bf16x8*)&Kc[key * 128 + ((ks * 32 + kgrp) ^ ((key & 7) << 3))];
        sacc[0][ni] = mfma16(kf, qf[0][ks], sacc[0][ni]);
        sacc[1][ni] = mfma16(kf, qf[1][ks], sacc[1][ni]);
      }
    }
    __builtin_amdgcn_s_setprio(0);

    // ---- softmax numerator in registers -> PV A-fragments + denom reduce ----
    // lane (lg,mrow): sacc[mi][ni][r] = S[key = t*32+ni*16+lg*4+r][q = mi-tile mrow]
    const float4 bb0 = *(const float4*)&Bias[t * 32 + lg * 4];
    const float4 bb1 = *(const float4*)&Bias[t * 32 + 16 + lg * 4];
    bf16x8 pf[2];
#pragma unroll
    for (int mi = 0; mi < 2; mi++) {
      unsigned u[4];
      float rs = 0.f;
#pragma unroll
      for (int ni = 0; ni < 2; ni++) {
        const float4 bb = ni ? bb1 : bb0;
        f32x4 s = sacc[mi][ni];
        float p0 = __builtin_exp2f(fminf(s[0] * c1 + bb.x, 80.f));
        float p1 = __builtin_exp2f(fminf(s[1] * c1 + bb.y, 80.f));
        float p2 = __builtin_exp2f(fminf(s[2] * c1 + bb.z, 80.f));
        float p3 = __builtin_exp2f(fminf(s[3] * c1 + bb.w, 80.f));
        rs += (p0 + p1) + (p2 + p3);
        unsigned ua, ub;
        asm("v_cvt_pk_bf16_f32 %0, %1, %2" : "=v"(ua) : "v"(p0), "v"(p1));
        asm("v_cvt_pk_bf16_f32 %0, %1, %2" : "=v"(ub) : "v"(p2), "v"(p3));
        u[ni * 2 + 0] = ua;
        u[ni * 2 + 1] = ub;
      }
      // denom: reduce rs over the 4 lane-groups (same mrow) -> all lanes
      {
        int sw = __builtin_amdgcn_ds_swizzle(__builtin_bit_cast(int, rs), 0x401F); // xor 16
        rs += __builtin_bit_cast(float, sw);
        float cpy = rs;
        asm("v_permlane32_swap_b32 %0, %1" : "+v"(rs), "+v"(cpy));
        rs += cpy;
        lsum[mi] += rs;
      }
      // exchange groups 0<->2, 1<->3; with the dsrow key-perm this yields
      // fragment words (j01,j23,j45,j67) = (u0,u1,u2,u3) for ALL lanes.
      asm("v_permlane32_swap_b32 %0, %1" : "+v"(u[0]), "+v"(u[2]));
      asm("v_permlane32_swap_b32 %0, %1" : "+v"(u[1]), "+v"(u[3]));
      __builtin_memcpy(&pf[mi], u, 16);
    }

    // ---- PV on tile t ----
    __builtin_amdgcn_s_setprio(1);
#pragma unroll
    for (int nt = 0; nt < 8; nt++) {
      bf16x8 raw = *(const bf16x8*)&VT[cur][(nt * 16 + mrow) * 40 + (kgrp ^ ((nt & 6) << 2))];
      bf16x8 vf = (nt & 1) ? __builtin_shufflevector(raw, raw, 4, 5, 6, 7, 0, 1, 2, 3) : raw;
      oacc[0][nt] = mfma16(pf[0], vf, oacc[0][nt]);
      oacc[1][nt] = mfma16(pf[1], vf, oacc[1][nt]);
    }
    __builtin_amdgcn_s_setprio(0);

    // ---- V(t+1) transpose into the other buffer ----
    if (t < 32) {
      unsigned short e[16];
      __builtin_memcpy(e, &vA, 16);
      __builtin_memcpy(e + 8, &vB, 16);
#pragma unroll
      for (int q8 = 0; q8 < 16; q8++)
        VT[nxt][(sch * 16 + q8) * 40 + kswz] = e[q8];
    }

    __syncthreads();  // single barrier: drains K-GLL(t+1) + VT(t+1) writes
  }

  // ---- epilogue ----
  // lsum[mi] holds denom for q-row (mi*16 + mrow); output rows are lg*4+r ->
  // fetch via bpermute from lane (lg'=0 group, mrow = lg*4+r).
  const size_t obase = (size_t)win * 225;
#pragma unroll
  for (int mi = 0; mi < 2; mi++) {
    f32x4 ri;
#pragma unroll
    for (int r = 0; r < 4; r++) {
      int v = __builtin_amdgcn_ds_bpermute((lg * 4 + r) * 4,
                                           __builtin_bit_cast(int, lsum[mi]));
      ri[r] = 1.0f / fmaxf(__builtin_bit_cast(float, v), 1e-30f);
    }
#pragma unroll
    for (int nt = 0; nt < 8; nt++) {
      f32x4 o = oacc[mi][nt];
#pragma unroll
      for (int r = 0; r < 4; r++) {
        int wrow = qbase + mi * 16 + lg * 4 + r;
        if (wrow < 225)
          op[(obase + wrow) * 512 + head * 128 + nt * 16 + mrow] = f2b(definan(o[r] * ri[r]));
      }
    }
  }
}

// ---------- launch ----------
extern "C" void kernel_launch(void* const* d_in, const int* in_sizes, int n_in,
                              void* d_out, int out_size, void* d_ws, size_t ws_size,
                              hipStream_t stream) {
  const float* x  = (const float*)d_in[0];
  const float* xp = (const float*)d_in[1];
  const float* qw = (const float*)d_in[2];
  const float* qb = (const float*)d_in[3];
  const float* pw = (const float*)d_in[4];
  const float* pb = (const float*)d_in[5];

  char* ws = (char*)d_ws;
  unsigned short* arena = (unsigned short*)ws;           // 18,008,064 el = 36,016,128 B
  unsigned short* x_b  = arena;                          // 16,588,800 el
  unsigned short* xp_b = arena + 16588800;
  unsigned short* qw_b = arena + 16957440;
  unsigned short* qb_b = arena + 17743872;
  unsigned short* pw_b = arena + 17745408;
  unsigned short* pb_b = arena + 18007552;
  unsigned short* qkv_ws = (unsigned short*)(ws + 36016128);   // 99,532,800 B
  unsigned short* kp     = (unsigned short*)(ws + 135549056);  // 1,638,400 B
  unsigned short* vp     = kp + 819200;                        // 1,638,400 B
  unsigned short* out_pre = x_b;  // overlay: x dead after gemm1

  // fp32 inputs -> bf16 arena
  convert_inputs<<<8793, 256, 0, stream>>>(x, xp, qw, qb, pw, pb, arena);

  // zero the padded pooled k/v (supplies unfold's zero padding AND the
  // guaranteed-zero rows used for padded attention keys)
  hipMemsetAsync(kp, 0, 2 * 819200 * sizeof(unsigned short), stream);

  // QKV projection for x tokens -> bf16 (XCD-chunked 1-D grid: 3048 = 8*381)
  gemm_bt<<<3048, 256, 0, stream>>>(x_b, qw_b, qb_b, qkv_ws, 32400, 512, 512, 512, 1536, 0, 12);

  // pooled k/v
  pooled_qkv<<<2880, 256, 0, stream>>>(xp_b, qw_b, qb_b, kp, vp);

  // fused attention -> bf16 pre-projection activations (XCD-swizzled 1-D grid)
  attn_win<<<1152, 256, 0, stream>>>(qkv_ws, kp, vp, out_pre);

  // output projection -> FLOAT32 d_out (XCD-chunked 1-D grid: 1016 = 8*127)
  gemm_bt<<<1016, 256, 0, stream>>>(out_pre, pw_b, pb_b, d_out, 32400, 512, 512, 512, 512, 1, 4);
}

// Round 4
// 401.474 us; speedup vs baseline: 1.7778x; 1.3231x over previous
//
#include <hip/hip_runtime.h>

// ---------- types / helpers ----------
typedef short bf16x8 __attribute__((ext_vector_type(8)));
typedef float f32x4 __attribute__((ext_vector_type(4)));

__device__ __forceinline__ float b2f(unsigned short u) {
  unsigned x = ((unsigned)u) << 16;
  float f;
  __builtin_memcpy(&f, &x, 4);
  return f;
}
__device__ __forceinline__ unsigned short f2b(float f) {
  unsigned x;
  __builtin_memcpy(&x, &f, 4);
  unsigned r = (x + 0x7FFFu + ((x >> 16) & 1u)) >> 16;  // RNE
  return (unsigned short)r;
}
__device__ __forceinline__ float definan(float f) {
  unsigned b;
  __builtin_memcpy(&b, &f, 4);
  if ((b & 0x7F800000u) == 0x7F800000u) return 0.f;
  return f;
}
__device__ __forceinline__ f32x4 mfma16(bf16x8 a, bf16x8 b, f32x4 c) {
  return __builtin_amdgcn_mfma_f32_16x16x32_bf16(a, b, c, 0, 0, 0);
}

#define GLL(g, l) __builtin_amdgcn_global_load_lds( \
    (const __attribute__((address_space(1))) void*)(g), \
    (__attribute__((address_space(3))) void*)(l), 16, 0, 0)

// ---------- input conversion: fp32 inputs -> bf16 arena ----------
__global__ __launch_bounds__(256)
void convert_inputs(const float* __restrict__ x, const float* __restrict__ xp,
                    const float* __restrict__ qw, const float* __restrict__ qb,
                    const float* __restrict__ pw, const float* __restrict__ pb,
                    unsigned short* __restrict__ arena) {
  long g = ((long)blockIdx.x * 256 + threadIdx.x) * 8;  // 8793*256*8 == 18008064 exactly
  const float* src;
  long off;
  if (g < 16588800L)      { src = x;  off = g; }
  else if (g < 16957440L) { src = xp; off = g - 16588800L; }
  else if (g < 17743872L) { src = qw; off = g - 16957440L; }
  else if (g < 17745408L) { src = qb; off = g - 17743872L; }
  else if (g < 18007552L) { src = pw; off = g - 17745408L; }
  else                    { src = pb; off = g - 18007552L; }
  float4 a = *(const float4*)(src + off);
  float4 b = *(const float4*)(src + off + 4);
  unsigned short o[8] = {f2b(a.x), f2b(a.y), f2b(a.z), f2b(a.w),
                         f2b(b.x), f2b(b.y), f2b(b.z), f2b(b.w)};
  uint4 pack;
  __builtin_memcpy(&pack, o, 16);
  *(uint4*)(arena + g) = pack;
}

// ---------- GEMM: C = A (MxK, row-major, bf16) * B^T (NxK, bf16) + bias ----------
// 1-D grid, XCD-chunked: each XCD gets a contiguous (bm-major, bn-fast) range so
// the A-tile is L2-resident across its bn-blocks. gridDim.x must be %8 == 0.
__global__ __launch_bounds__(256, 2)
void gemm_bt(const unsigned short* __restrict__ A, const unsigned short* __restrict__ B,
             const unsigned short* __restrict__ bias, void* __restrict__ Co,
             int M, int K, int lda, int ldb, int ldc, int wf32, int nbn) {
  __shared__ unsigned short Al[4096];
  __shared__ unsigned short Bl[4096];
  const int tid = threadIdx.x;
  const int i = blockIdx.x;
  const int g = (i & 7) * ((int)gridDim.x >> 3) + (i >> 3);
  const int bm = g / nbn, bn = g - bm * nbn;
  const int lane = tid & 63;
  const int wid = tid >> 6;
  const int wm = (wid >> 1) * 64, wn = (wid & 1) * 64;
  const int mrow = lane & 15, kgrp = (lane >> 4) * 8;

  f32x4 acc[4][4] = {};

  const int c0 = tid, c1 = tid + 256;
  const int r0 = c0 >> 2, o0 = (c0 & 3) * 8;
  const int r1 = c1 >> 2, o1 = (c1 & 3) * 8;
  int am0 = bm * 128 + r0; if (am0 > M - 1) am0 = M - 1;
  int am1 = bm * 128 + r1; if (am1 > M - 1) am1 = M - 1;
  const unsigned short* ap0 = A + (size_t)am0 * lda + o0;
  const unsigned short* ap1 = A + (size_t)am1 * lda + o1;
  const unsigned short* bp0 = B + (size_t)(bn * 128 + r0) * ldb + o0;
  const unsigned short* bp1 = B + (size_t)(bn * 128 + r1) * ldb + o1;

  const int nkt = K >> 5;
  for (int kt = 0; kt < nkt; kt++) {
    GLL(ap0, &Al[c0 * 8]);
    GLL(ap1, &Al[c1 * 8]);
    GLL(bp0, &Bl[c0 * 8]);
    GLL(bp1, &Bl[c1 * 8]);
    ap0 += 32; ap1 += 32; bp0 += 32; bp1 += 32;
    __syncthreads();
    bf16x8 af[4], bfr[4];
#pragma unroll
    for (int mi = 0; mi < 4; mi++)
      af[mi] = *(const bf16x8*)&Al[(wm + mi * 16 + mrow) * 32 + kgrp];
#pragma unroll
    for (int ni = 0; ni < 4; ni++)
      bfr[ni] = *(const bf16x8*)&Bl[(wn + ni * 16 + mrow) * 32 + kgrp];
#pragma unroll
    for (int mi = 0; mi < 4; mi++)
#pragma unroll
      for (int ni = 0; ni < 4; ni++)
        acc[mi][ni] = mfma16(af[mi], bfr[ni], acc[mi][ni]);
    __syncthreads();
  }

#pragma unroll
  for (int ni = 0; ni < 4; ni++) {
    const int gcol = bn * 128 + wn + ni * 16 + mrow;
    const float bv = b2f(bias[gcol]);
#pragma unroll
    for (int mi = 0; mi < 4; mi++) {
      f32x4 v = acc[mi][ni];
#pragma unroll
      for (int r = 0; r < 4; r++) {
        int grow = bm * 128 + wm + mi * 16 + (lane >> 4) * 4 + r;
        if (grow < M) {
          float val = definan(v[r] + bv);
          if (wf32) ((float*)Co)[(size_t)grow * ldc + gcol] = val;
          else      ((unsigned short*)Co)[(size_t)grow * ldc + gcol] = f2b(val);
        }
      }
    }
  }
}

// ---------- pooled k/v GEMM: xp_b (720x512, contiguous) * Wkv^T (1024x512) ----------
// Same 128^2 MFMA tile as gemm_bt; epilogue scatters row r = (ph*12+pw)*5+t into
// the padded (5,16,20,512) kp/vp arrays. Replaces the 163us scalar pooled_qkv.
__global__ __launch_bounds__(256, 2)
void pooled_gemm(const unsigned short* __restrict__ A, const unsigned short* __restrict__ B,
                 const unsigned short* __restrict__ bias, unsigned short* __restrict__ kp,
                 unsigned short* __restrict__ vp) {
  __shared__ unsigned short Al[4096];
  __shared__ unsigned short Bl[4096];
  const int tid = threadIdx.x;
  const int bm = blockIdx.x, bn = blockIdx.y;
  const int lane = tid & 63;
  const int wid = tid >> 6;
  const int wm = (wid >> 1) * 64, wn = (wid & 1) * 64;
  const int mrow = lane & 15, kgrp = (lane >> 4) * 8;

  f32x4 acc[4][4] = {};

  const int c0 = tid, c1 = tid + 256;
  const int r0 = c0 >> 2, o0 = (c0 & 3) * 8;
  const int r1 = c1 >> 2, o1 = (c1 & 3) * 8;
  int am0 = bm * 128 + r0; if (am0 > 719) am0 = 719;
  int am1 = bm * 128 + r1; if (am1 > 719) am1 = 719;
  const unsigned short* ap0 = A + (size_t)am0 * 512 + o0;
  const unsigned short* ap1 = A + (size_t)am1 * 512 + o1;
  const unsigned short* bp0 = B + (size_t)(bn * 128 + r0) * 512 + o0;
  const unsigned short* bp1 = B + (size_t)(bn * 128 + r1) * 512 + o1;

  for (int kt = 0; kt < 16; kt++) {
    GLL(ap0, &Al[c0 * 8]);
    GLL(ap1, &Al[c1 * 8]);
    GLL(bp0, &Bl[c0 * 8]);
    GLL(bp1, &Bl[c1 * 8]);
    ap0 += 32; ap1 += 32; bp0 += 32; bp1 += 32;
    __syncthreads();
    bf16x8 af[4], bfr[4];
#pragma unroll
    for (int mi = 0; mi < 4; mi++)
      af[mi] = *(const bf16x8*)&Al[(wm + mi * 16 + mrow) * 32 + kgrp];
#pragma unroll
    for (int ni = 0; ni < 4; ni++)
      bfr[ni] = *(const bf16x8*)&Bl[(wn + ni * 16 + mrow) * 32 + kgrp];
#pragma unroll
    for (int mi = 0; mi < 4; mi++)
#pragma unroll
      for (int ni = 0; ni < 4; ni++)
        acc[mi][ni] = mfma16(af[mi], bfr[ni], acc[mi][ni]);
    __syncthreads();
  }

#pragma unroll
  for (int ni = 0; ni < 4; ni++) {
    const int gcol = bn * 128 + wn + ni * 16 + mrow;   // 0..1023
    const float bv = b2f(bias[gcol]);
    unsigned short* dst = (gcol < 512) ? kp : vp;
    const int ncol = gcol & 511;
#pragma unroll
    for (int mi = 0; mi < 4; mi++) {
      f32x4 v = acc[mi][ni];
#pragma unroll
      for (int r = 0; r < 4; r++) {
        int grow = bm * 128 + wm + mi * 16 + (lane >> 4) * 4 + r;
        if (grow < 720) {
          int ph = grow / 60;
          int rem = grow - ph * 60;
          int pw2 = rem / 5;
          int t = rem - pw2 * 5;
          size_t off = ((size_t)(t * 16 + ph + 2) * 20 + (pw2 + 4)) * 512;
          dst[off + ncol] = f2b(definan(v[r] + bv));
        }
      }
    }
  }
}

// ---------- fused window attention ----------
// One block per (window, q-half, head): 256 threads = 4 waves, 32 q-rows/wave.
// XCD-swizzled 1-D grid; single barrier per 32-key tile; K via double-buffered
// global_load_lds (pre-swizzled source); V double-buffered transposed in LDS;
// P fully in registers via swapped QK^T + cvt_pk + permlane32_swap.
// Softmax denominator via VALU cross-lane reduce (no mfma-with-ones, no lacc):
// keeps total unified VGPR+AGPR <= 170 -> 3 waves/SIMD.
__global__ __launch_bounds__(256, 3)
void attn_win(const unsigned short* __restrict__ qkv, const unsigned short* __restrict__ kp,
              const unsigned short* __restrict__ vp, unsigned short* __restrict__ op) {
  const int bi = blockIdx.x;
  const int win = (bi & 7) * 18 + (bi >> 6);
  const int sub = (bi >> 3) & 7;
  const int qh = sub & 1, head = sub >> 1;
  const int wh = win / 12, ww = win - wh * 12;
  const int tid = threadIdx.x;
  const int lane = tid & 63, wv = tid >> 6;
  const int mrow = lane & 15, kgrp = (lane >> 4) * 8;
  const int lg = lane >> 4;

  __shared__ unsigned short Kl[2][32 * 128];   // linear GLL dest, chunk-XOR-swizzled
  __shared__ unsigned short VT[2][128 * 40];   // transposed V, col ^ (sch<<2) swizzle
  __shared__ float Bias[1056];
  __shared__ int Tok[1056];                    // K element-offsets relative to qkv

  const int kpd = (int)(kp - qkv);             // pooled K region delta (elements)
  const int vpd = (int)(vp - kp);              // pooled V delta from K (elements)

  // ---- build token-offset + bias tables (once per block) ----
  for (int i = tid; i < 1056; i += 256) {
    float b = 0.f;
    int off;
    if (i < 225) {
      int t = i / 45, rem = i - t * 45;
      int ii = rem / 9, jj = rem - ii * 9;
      int g = (t * 60 + wh * 5 + ii) * 108 + ww * 9 + jj;
      off = g * 1536 + 512 + head * 128;
    } else if (i < 825) {
      int rr = i - 225;
      int t = rr / 120, v = rr - t * 120;
      int p = v / 30, q = v - p * 30;
      int ii, jj;
      if (p == 0) {
        if (q < 12) { ii = q >> 2; jj = 5 + (q & 3); }
        else { int q2 = q - 12; int d9 = q2 / 9; ii = 3 + d9; jj = q2 - d9 * 9; }
      } else if (p == 1) {
        if (q < 12) { ii = q >> 2; jj = q & 3; }
        else { int q2 = q - 12; int d9 = q2 / 9; ii = 3 + d9; jj = q2 - d9 * 9; }
      } else if (p == 2) {
        if (q < 18) { int d9 = q / 9; ii = d9; jj = q - d9 * 9; }
        else { int q2 = q - 18; ii = 2 + (q2 >> 2); jj = 5 + (q2 & 3); }
      } else {
        if (q < 18) { int d9 = q / 9; ii = d9; jj = q - d9 * 9; }
        else { int q2 = q - 18; ii = 2 + (q2 >> 2); jj = q2 & 3; }
      }
      int gh = wh * 5 + ii + ((p < 2) ? 2 : -2);
      if (gh >= 60) gh -= 60; if (gh < 0) gh += 60;
      int gw = ww * 9 + jj + (((p & 1) == 0) ? 4 : -4);
      if (gw >= 108) gw -= 108; if (gw < 0) gw += 108;
      int g = (t * 60 + gh) * 108 + gw;
      off = g * 1536 + 512 + head * 128;
    } else if (i < 1050) {
      int pidx = i - 825;
      int t = pidx / 45, rem = pidx - t * 45;
      int fi = rem / 9, fj = rem - fi * 9;
      int ph = wh + fi - 2, pw2 = ww + fj - 4;
      if (ph < 0 || ph >= 12 || pw2 < 0 || pw2 >= 12) b = -144.269504089f;  // -100*log2(e)
      off = kpd + ((t * 16 + wh + fi) * 20 + (ww + fj)) * 512 + head * 128;
    } else {
      b = -100000.f;
      off = kpd;  // kp/vp rows < 44*512 are never written -> guaranteed zeros
    }
    Bias[i] = b;
    Tok[i] = off;
  }

  // ---- Q fragments (held in registers for whole kernel) ----
  const int qbase = qh * 128 + wv * 32;
  bf16x8 qf[2][4];
#pragma unroll
  for (int mi = 0; mi < 2; mi++) {
    int wrow = qbase + mi * 16 + mrow;
    if (wrow < 225) {
      int t = wrow / 45, rem = wrow - t * 45;
      int ii = rem / 9, jj = rem - ii * 9;
      int g = (t * 60 + wh * 5 + ii) * 108 + ww * 9 + jj;
      const unsigned short* qp = qkv + (size_t)g * 1536 + head * 128;
#pragma unroll
      for (int ks = 0; ks < 4; ks++)
        qf[mi][ks] = *(const bf16x8*)(qp + ks * 32 + kgrp);
    } else {
      bf16x8 z = {0, 0, 0, 0, 0, 0, 0, 0};
#pragma unroll
      for (int ks = 0; ks < 4; ks++) qf[mi][ks] = z;
    }
  }

  // ---- per-thread staging constants ----
  const int ci0 = wv * 128 + lane;
  const int ci1 = ci0 + 64;
  const int kk0 = ci0 >> 4, cc0 = ((ci0 & 15) ^ (kk0 & 7)) * 8;
  const int kk1 = ci1 >> 4, cc1 = ((ci1 & 15) ^ (kk1 & 7)) * 8;
  const int srow = tid >> 3, sch = tid & 7;
  const int kswz = srow ^ (sch << 2);
  const int sb = (srow >> 2) & 3;
  const int dsrow = srow + (sb == 1 ? 4 : (sb == 2 ? -4 : 0));

  f32x4 oacc[2][8] = {};
  float lsum[2] = {0.f, 0.f};  // softmax denom per q-row (lane-indexed by mrow)
  const float c1 = 0.12752713f;  // log2(e)/sqrt(128)

  __syncthreads();  // Tok/Bias ready

  // ---- prologue: stage tile 0 ----
  GLL(qkv + Tok[kk0] + cc0, &Kl[0][ci0 * 8]);
  GLL(qkv + Tok[kk1] + cc1, &Kl[0][ci1 * 8]);
  {
    const unsigned short* vsrc = qkv + (size_t)Tok[dsrow] + 512 + sch * 16;
    uint4 vA = *(const uint4*)vsrc;
    uint4 vB = *(const uint4*)(vsrc + 8);
    unsigned short e[16];
    __builtin_memcpy(e, &vA, 16);
    __builtin_memcpy(e + 8, &vB, 16);
#pragma unroll
    for (int q8 = 0; q8 < 16; q8++)
      VT[0][(sch * 16 + q8) * 40 + kswz] = e[q8];
  }
  __syncthreads();  // drains GLL + VT writes

  for (int t = 0; t < 33; t++) {
    const int cur = t & 1, nxt = cur ^ 1;
    const unsigned short* Kc = &Kl[cur][0];

    // ---- issue next-tile staging (hidden under this tile's compute) ----
    uint4 vA, vB;
    if (t < 32) {
      const int base = (t + 1) * 32;
      GLL(qkv + Tok[base + kk0] + cc0, &Kl[nxt][ci0 * 8]);
      GLL(qkv + Tok[base + kk1] + cc1, &Kl[nxt][ci1 * 8]);
      int widx = base + dsrow;
      int vd = (widx < 825) ? 512 : vpd;
      const unsigned short* vsrc = qkv + (size_t)Tok[widx] + vd + sch * 16;
      vA = *(const uint4*)vsrc;
      vB = *(const uint4*)(vsrc + 8);
    }

    // ---- S^T = K·Q^T on tile t (swapped operands; swizzled K reads) ----
    f32x4 sacc[2][2] = {};
    __builtin_amdgcn_s_setprio(1);
#pragma unroll
    for (int ks = 0; ks < 4; ks++) {
#pragma unroll
      for (int ni = 0; ni < 2; ni++) {
        int key = ni * 16 + mrow;
        bf16x8 kf = *(const bf16x8*)&Kc[key * 128 + ((ks * 32 + kgrp) ^ ((key & 7) << 3))];
        sacc[0][ni] = mfma16(kf, qf[0][ks], sacc[0][ni]);
        sacc[1][ni] = mfma16(kf, qf[1][ks], sacc[1][ni]);
      }
    }
    __builtin_amdgcn_s_setprio(0);

    // ---- softmax numerator in registers -> PV A-fragments + denom reduce ----
    // lane (lg,mrow): sacc[mi][ni][r] = S[key = t*32+ni*16+lg*4+r][q = mi-tile mrow]
    const float4 bb0 = *(const float4*)&Bias[t * 32 + lg * 4];
    const float4 bb1 = *(const float4*)&Bias[t * 32 + 16 + lg * 4];
    bf16x8 pf[2];
#pragma unroll
    for (int mi = 0; mi < 2; mi++) {
      unsigned u[4];
      float rs = 0.f;
#pragma unroll
      for (int ni = 0; ni < 2; ni++) {
        const float4 bb = ni ? bb1 : bb0;
        f32x4 s = sacc[mi][ni];
        float p0 = __builtin_exp2f(fminf(s[0] * c1 + bb.x, 80.f));
        float p1 = __builtin_exp2f(fminf(s[1] * c1 + bb.y, 80.f));
        float p2 = __builtin_exp2f(fminf(s[2] * c1 + bb.z, 80.f));
        float p3 = __builtin_exp2f(fminf(s[3] * c1 + bb.w, 80.f));
        rs += (p0 + p1) + (p2 + p3);
        unsigned ua, ub;
        asm("v_cvt_pk_bf16_f32 %0, %1, %2" : "=v"(ua) : "v"(p0), "v"(p1));
        asm("v_cvt_pk_bf16_f32 %0, %1, %2" : "=v"(ub) : "v"(p2), "v"(p3));
        u[ni * 2 + 0] = ua;
        u[ni * 2 + 1] = ub;
      }
      // denom: reduce rs over the 4 lane-groups (same mrow) -> all lanes
      {
        int sw = __builtin_amdgcn_ds_swizzle(__builtin_bit_cast(int, rs), 0x401F); // xor 16
        rs += __builtin_bit_cast(float, sw);
        float cpy = rs;
        asm("v_permlane32_swap_b32 %0, %1" : "+v"(rs), "+v"(cpy));
        rs += cpy;
        lsum[mi] += rs;
      }
      // exchange groups 0<->2, 1<->3; with the dsrow key-perm this yields
      // fragment words (j01,j23,j45,j67) = (u0,u1,u2,u3) for ALL lanes.
      asm("v_permlane32_swap_b32 %0, %1" : "+v"(u[0]), "+v"(u[2]));
      asm("v_permlane32_swap_b32 %0, %1" : "+v"(u[1]), "+v"(u[3]));
      __builtin_memcpy(&pf[mi], u, 16);
    }

    // ---- PV on tile t ----
    __builtin_amdgcn_s_setprio(1);
#pragma unroll
    for (int nt = 0; nt < 8; nt++) {
      bf16x8 raw = *(const bf16x8*)&VT[cur][(nt * 16 + mrow) * 40 + (kgrp ^ ((nt & 6) << 2))];
      bf16x8 vf = (nt & 1) ? __builtin_shufflevector(raw, raw, 4, 5, 6, 7, 0, 1, 2, 3) : raw;
      oacc[0][nt] = mfma16(pf[0], vf, oacc[0][nt]);
      oacc[1][nt] = mfma16(pf[1], vf, oacc[1][nt]);
    }
    __builtin_amdgcn_s_setprio(0);

    // ---- V(t+1) transpose into the other buffer ----
    if (t < 32) {
      unsigned short e[16];
      __builtin_memcpy(e, &vA, 16);
      __builtin_memcpy(e + 8, &vB, 16);
#pragma unroll
      for (int q8 = 0; q8 < 16; q8++)
        VT[nxt][(sch * 16 + q8) * 40 + kswz] = e[q8];
    }

    __syncthreads();  // single barrier: drains K-GLL(t+1) + VT(t+1) writes
  }

  // ---- epilogue ----
  // lsum[mi] holds denom for q-row (mi*16 + mrow); output rows are lg*4+r ->
  // fetch via bpermute from lane (lg'=0 group, mrow = lg*4+r).
  const size_t obase = (size_t)win * 225;
#pragma unroll
  for (int mi = 0; mi < 2; mi++) {
    f32x4 ri;
#pragma unroll
    for (int r = 0; r < 4; r++) {
      int v = __builtin_amdgcn_ds_bpermute((lg * 4 + r) * 4,
                                           __builtin_bit_cast(int, lsum[mi]));
      ri[r] = 1.0f / fmaxf(__builtin_bit_cast(float, v), 1e-30f);
    }
#pragma unroll
    for (int nt = 0; nt < 8; nt++) {
      f32x4 o = oacc[mi][nt];
#pragma unroll
      for (int r = 0; r < 4; r++) {
        int wrow = qbase + mi * 16 + lg * 4 + r;
        if (wrow < 225)
          op[(obase + wrow) * 512 + head * 128 + nt * 16 + mrow] = f2b(definan(o[r] * ri[r]));
      }
    }
  }
}

// ---------- launch ----------
extern "C" void kernel_launch(void* const* d_in, const int* in_sizes, int n_in,
                              void* d_out, int out_size, void* d_ws, size_t ws_size,
                              hipStream_t stream) {
  const float* x  = (const float*)d_in[0];
  const float* xp = (const float*)d_in[1];
  const float* qw = (const float*)d_in[2];
  const float* qb = (const float*)d_in[3];
  const float* pw = (const float*)d_in[4];
  const float* pb = (const float*)d_in[5];

  char* ws = (char*)d_ws;
  unsigned short* arena = (unsigned short*)ws;           // 18,008,064 el = 36,016,128 B
  unsigned short* x_b  = arena;                          // 16,588,800 el
  unsigned short* xp_b = arena + 16588800;
  unsigned short* qw_b = arena + 16957440;
  unsigned short* qb_b = arena + 17743872;
  unsigned short* pw_b = arena + 17745408;
  unsigned short* pb_b = arena + 18007552;
  unsigned short* qkv_ws = (unsigned short*)(ws + 36016128);   // 99,532,800 B
  unsigned short* kp     = (unsigned short*)(ws + 135549056);  // 1,638,400 B
  unsigned short* vp     = kp + 819200;                        // 1,638,400 B
  unsigned short* out_pre = x_b;  // overlay: x dead after gemm1

  // fp32 inputs -> bf16 arena
  convert_inputs<<<8793, 256, 0, stream>>>(x, xp, qw, qb, pw, pb, arena);

  // zero the padded pooled k/v (supplies unfold's zero padding AND the
  // guaranteed-zero rows used for padded attention keys)
  hipMemsetAsync(kp, 0, 2 * 819200 * sizeof(unsigned short), stream);

  // QKV projection for x tokens -> bf16 (XCD-chunked 1-D grid: 3048 = 8*381)
  gemm_bt<<<3048, 256, 0, stream>>>(x_b, qw_b, qb_b, qkv_ws, 32400, 512, 512, 512, 1536, 0, 12);

  // pooled k/v via MFMA GEMM (xp_b is a contiguous 720x512 matrix; weight rows
  // 512..1535 of qkv_w; scatter epilogue into padded kp/vp)
  dim3 gp(6, 8);
  pooled_gemm<<<gp, 256, 0, stream>>>(xp_b, qw_b + 512 * 512, qb_b + 512, kp, vp);

  // fused attention -> bf16 pre-projection activations (XCD-swizzled 1-D grid)
  attn_win<<<1152, 256, 0, stream>>>(qkv_ws, kp, vp, out_pre);

  // output projection -> FLOAT32 d_out (XCD-chunked 1-D grid: 1016 = 8*127)
  gemm_bt<<<1016, 256, 0, stream>>>(out_pre, pw_b, pb_b, d_out, 32400, 512, 512, 512, 512, 1, 4);
}